// Round 4
// baseline (59.503 us; speedup 1.0000x reference)
//
#include <hip/hip_runtime.h>

#define NB 16384       // bags
#define DIM 128
#define PRED_W 512     // 4 * DIM
#define NPART NB       // one partial per block

// One wave pools one (bag, feature). Lanes 0-31 carry the EVEN bag elements,
// lanes 32-63 the ODD ones: a single global_load_dwordx4 (16B/lane) fetches
// two full 512B rows per instruction. Guards are wave-uniform (s_cbranch),
// so no divergence and no wasted gathers beyond <=1 half-row per bag.
template<int L>
__device__ __forceinline__ void pool_pair(
    const int* __restrict__ idx, const int* __restrict__ len,
    const float* __restrict__ emb, const float* __restrict__ pw,
    int b, int lane, float4& acc)
{
    const int n = len[b];                       // wave-uniform
    const int* __restrict__ bag = idx + (size_t)b * L;  // uniform -> s_load
    const int half = lane >> 5;                 // 0: even element, 1: odd
    const int col  = (lane & 31) << 2;          // float offset within row

    constexpr int P = L / 2;                    // pairs (L is even)

    // Issue all needed paired gathers back-to-back.
    float4 v[P];
    #pragma unroll
    for (int j = 0; j < P; ++j)
        if (2 * j < n)                          // wave-uniform
            v[j] = *reinterpret_cast<const float4*>(
                emb + (size_t)bag[2 * j + half] * DIM + col);

    // Consume. Weight 0 masks the odd element when it's past n
    // (its index is still a valid row of the table).
    #pragma unroll
    for (int j = 0; j < P; ++j)
        if (2 * j < n) {
            const int l = 2 * j + half;
            const float w = (l < n) ? pw[l] : 0.f;
            acc.x = fmaf(w, v[j].x, acc.x);
            acc.y = fmaf(w, v[j].y, acc.y);
            acc.z = fmaf(w, v[j].z, acc.z);
            acc.w = fmaf(w, v[j].w, acc.w);
        }
}

__global__ __launch_bounds__(256) void pool4_kernel(
    const int* __restrict__ idx0, const int* __restrict__ len0,
    const float* __restrict__ emb0, const float* __restrict__ pw0,
    const int* __restrict__ idx1, const int* __restrict__ len1,
    const float* __restrict__ emb1, const float* __restrict__ pw1,
    const int* __restrict__ idx2, const int* __restrict__ len2,
    const float* __restrict__ emb2, const float* __restrict__ pw2,
    const int* __restrict__ idx3, const int* __restrict__ len3,
    const float* __restrict__ emb3, const float* __restrict__ pw3,
    float* __restrict__ pred,      // d_out + 1 (4-byte aligned only)
    float* __restrict__ partials)  // d_ws, NPART floats
{
    const int b    = blockIdx.x;
    const int wave = threadIdx.x >> 6;   // 0..3 -> feature id
    const int lane = threadIdx.x & 63;

    float4 acc = {0.f, 0.f, 0.f, 0.f};
    switch (wave) {
        case 0:  pool_pair<10>(idx0, len0, emb0, pw0, b, lane, acc); break;
        case 1:  pool_pair<10>(idx1, len1, emb1, pw1, b, lane, acc); break;
        case 2:  pool_pair<12>(idx2, len2, emb2, pw2, b, lane, acc); break;
        default: pool_pair<12>(idx3, len3, emb3, pw3, b, lane, acc); break;
    }

    // Fold odd-element half (lanes 32-63) into lanes 0-31.
    acc.x += __shfl_down(acc.x, 32, 64);
    acc.y += __shfl_down(acc.y, 32, 64);
    acc.z += __shfl_down(acc.z, 32, 64);
    acc.w += __shfl_down(acc.w, 32, 64);

    const int lane32 = lane & 31;
    if (lane < 32) {
        // lane i holds dims [4i, 4i+3] of this feature's 128-dim slice.
        float* o = pred + (size_t)b * PRED_W + wave * DIM + 4 * lane32;
        o[0] = acc.x; o[1] = acc.y; o[2] = acc.z; o[3] = acc.w;
    }

    // loss partial: reduce lanes 0-31 (lanes 32-63 now hold garbage halves,
    // mask them to zero first).
    float s = (lane < 32) ? (acc.x + acc.y) + (acc.z + acc.w) : 0.f;
    #pragma unroll
    for (int off = 32; off; off >>= 1) s += __shfl_down(s, off, 64);

    __shared__ float ws[4];
    if (lane == 0) ws[wave] = s;
    __syncthreads();
    if (threadIdx.x == 0) partials[b] = ws[0] + ws[1] + ws[2] + ws[3];
}

__global__ __launch_bounds__(1024) void reduce_kernel(
    const float* __restrict__ partials, float* __restrict__ loss_out)
{
    // 16384 floats = 4096 float4s, 1024 threads x 4
    float s = 0.f;
    const float4* p4 = reinterpret_cast<const float4*>(partials);
    #pragma unroll
    for (int i = 0; i < 4; ++i) {
        float4 v = p4[threadIdx.x + i * 1024];
        s += (v.x + v.y) + (v.z + v.w);
    }

    #pragma unroll
    for (int off = 32; off; off >>= 1) s += __shfl_down(s, off, 64);

    __shared__ float ws[16];
    const int wave = threadIdx.x >> 6, lane = threadIdx.x & 63;
    if (lane == 0) ws[wave] = s;
    __syncthreads();
    if (threadIdx.x == 0) {
        float t = 0.f;
        #pragma unroll
        for (int i = 0; i < 16; ++i) t += ws[i];
        loss_out[0] = t / (float)((size_t)NB * PRED_W);
    }
}

extern "C" void kernel_launch(void* const* d_in, const int* in_sizes, int n_in,
                              void* d_out, int out_size, void* d_ws, size_t ws_size,
                              hipStream_t stream) {
    // setup_inputs() dict order: per feature f: idx{f}, len{f}, emb{f}, pw{f}
    const int*   idx0 = (const int*)  d_in[0];
    const int*   len0 = (const int*)  d_in[1];
    const float* emb0 = (const float*)d_in[2];
    const float* pw0  = (const float*)d_in[3];
    const int*   idx1 = (const int*)  d_in[4];
    const int*   len1 = (const int*)  d_in[5];
    const float* emb1 = (const float*)d_in[6];
    const float* pw1  = (const float*)d_in[7];
    const int*   idx2 = (const int*)  d_in[8];
    const int*   len2 = (const int*)  d_in[9];
    const float* emb2 = (const float*)d_in[10];
    const float* pw2  = (const float*)d_in[11];
    const int*   idx3 = (const int*)  d_in[12];
    const int*   len3 = (const int*)  d_in[13];
    const float* emb3 = (const float*)d_in[14];
    const float* pw3  = (const float*)d_in[15];

    float* out = (float*)d_out;          // out[0] = loss, out+1 = pred
    float* partials = (float*)d_ws;      // NPART floats

    pool4_kernel<<<NB, 256, 0, stream>>>(
        idx0, len0, emb0, pw0,
        idx1, len1, emb1, pw1,
        idx2, len2, emb2, pw2,
        idx3, len3, emb3, pw3,
        out + 1, partials);

    reduce_kernel<<<1, 1024, 0, stream>>>(partials, out);
}

// Round 5
// 44.331 us; speedup vs baseline: 1.3422x; 1.3422x over previous
//
#include <hip/hip_runtime.h>
#include <stdint.h>

#define NB 16384       // bags
#define DIM 128
#define PRED_W 512     // 4 * DIM
#define NPART NB       // one partial per block

typedef float f32x2 __attribute__((ext_vector_type(2)));

// Per-row prep: clamp OOB slots to row 0 (L1/L2-hot, no extra HBM traffic)
// with weight 0. All values wave-uniform -> scalar regs.
#define DECL_ROW(l) \
    const int   r##l = ((l) < n) ? bag[l] : 0;            \
    const float w##l = ((l) < n) ? pw[l]  : 0.f;          \
    const float* p##l = emb + (size_t)r##l * DIM;

// Forced-issue gather: asm volatile keeps all L loads back-to-back (MLP = L).
// Row base in SGPR pair (uniform), per-lane byte offset voff = lane*8 shared.
#define ISSUE(l) \
    f32x2 v##l;                                           \
    asm volatile("global_load_dwordx2 %0, %1, %2"         \
                 : "=v"(v##l) : "v"(voff), "s"(p##l) : "memory");

#define FMA(l) \
    ax = fmaf(w##l, v##l[0], ax);                         \
    ay = fmaf(w##l, v##l[1], ay);

#define ROWS10(M) M(0) M(1) M(2) M(3) M(4) M(5) M(6) M(7) M(8) M(9)
#define ROWS12(M) ROWS10(M) M(10) M(11)

__device__ __forceinline__ void pool10(
    const int* __restrict__ idx, const int* __restrict__ len,
    const float* __restrict__ emb, const float* __restrict__ pw,
    int b, int voff, float& ax, float& ay)
{
    const int n = len[b];                        // wave-uniform
    const int* __restrict__ bag = idx + (size_t)b * 10;
    ROWS10(DECL_ROW)
    ROWS10(ISSUE)
    // Tie every payload through the waitcnt so consumers can't hoist above it.
    asm volatile("s_waitcnt vmcnt(0)"
                 : "+v"(v0), "+v"(v1), "+v"(v2), "+v"(v3), "+v"(v4),
                   "+v"(v5), "+v"(v6), "+v"(v7), "+v"(v8), "+v"(v9));
    __builtin_amdgcn_sched_barrier(0);
    ROWS10(FMA)
}

__device__ __forceinline__ void pool12(
    const int* __restrict__ idx, const int* __restrict__ len,
    const float* __restrict__ emb, const float* __restrict__ pw,
    int b, int voff, float& ax, float& ay)
{
    const int n = len[b];                        // wave-uniform
    const int* __restrict__ bag = idx + (size_t)b * 12;
    ROWS12(DECL_ROW)
    ROWS12(ISSUE)
    asm volatile("s_waitcnt vmcnt(0)"
                 : "+v"(v0), "+v"(v1), "+v"(v2), "+v"(v3), "+v"(v4),
                   "+v"(v5), "+v"(v6), "+v"(v7), "+v"(v8), "+v"(v9),
                   "+v"(v10), "+v"(v11));
    __builtin_amdgcn_sched_barrier(0);
    ROWS12(FMA)
}

__global__ __launch_bounds__(256) void pool4_kernel(
    const int* __restrict__ idx0, const int* __restrict__ len0,
    const float* __restrict__ emb0, const float* __restrict__ pw0,
    const int* __restrict__ idx1, const int* __restrict__ len1,
    const float* __restrict__ emb1, const float* __restrict__ pw1,
    const int* __restrict__ idx2, const int* __restrict__ len2,
    const float* __restrict__ emb2, const float* __restrict__ pw2,
    const int* __restrict__ idx3, const int* __restrict__ len3,
    const float* __restrict__ emb3, const float* __restrict__ pw3,
    float* __restrict__ pred,      // d_out + 1 (4-byte aligned only)
    float* __restrict__ partials)  // d_ws, NPART floats
{
    const int b    = blockIdx.x;
    const int wave = threadIdx.x >> 6;   // 0..3 -> feature id
    const int lane = threadIdx.x & 63;
    const int voff = lane << 3;          // byte offset within the 512B row

    float ax = 0.f, ay = 0.f;
    switch (wave) {
        case 0:  pool10(idx0, len0, emb0, pw0, b, voff, ax, ay); break;
        case 1:  pool10(idx1, len1, emb1, pw1, b, voff, ax, ay); break;
        case 2:  pool12(idx2, len2, emb2, pw2, b, voff, ax, ay); break;
        default: pool12(idx3, len3, emb3, pw3, b, voff, ax, ay); break;
    }

    // pred store: scalar (pred base is only 4B aligned)
    float* o = pred + (size_t)b * PRED_W + wave * DIM + 2 * lane;
    o[0] = ax;
    o[1] = ay;

    // loss partial: wave reduce -> block reduce -> one partial per block
    float s = ax + ay;
    #pragma unroll
    for (int off = 32; off; off >>= 1) s += __shfl_down(s, off, 64);

    __shared__ float ws[4];
    if (lane == 0) ws[wave] = s;
    __syncthreads();
    if (threadIdx.x == 0) partials[b] = ws[0] + ws[1] + ws[2] + ws[3];
}

__global__ __launch_bounds__(1024) void reduce_kernel(
    const float* __restrict__ partials, float* __restrict__ loss_out)
{
    // 16384 floats = 4096 float4s, 1024 threads x 4
    float s = 0.f;
    const float4* p4 = reinterpret_cast<const float4*>(partials);
    #pragma unroll
    for (int i = 0; i < 4; ++i) {
        float4 v = p4[threadIdx.x + i * 1024];
        s += (v.x + v.y) + (v.z + v.w);
    }

    #pragma unroll
    for (int off = 32; off; off >>= 1) s += __shfl_down(s, off, 64);

    __shared__ float ws[16];
    const int wave = threadIdx.x >> 6, lane = threadIdx.x & 63;
    if (lane == 0) ws[wave] = s;
    __syncthreads();
    if (threadIdx.x == 0) {
        float t = 0.f;
        #pragma unroll
        for (int i = 0; i < 16; ++i) t += ws[i];
        loss_out[0] = t / (float)((size_t)NB * PRED_W);
    }
}

extern "C" void kernel_launch(void* const* d_in, const int* in_sizes, int n_in,
                              void* d_out, int out_size, void* d_ws, size_t ws_size,
                              hipStream_t stream) {
    // setup_inputs() dict order: per feature f: idx{f}, len{f}, emb{f}, pw{f}
    const int*   idx0 = (const int*)  d_in[0];
    const int*   len0 = (const int*)  d_in[1];
    const float* emb0 = (const float*)d_in[2];
    const float* pw0  = (const float*)d_in[3];
    const int*   idx1 = (const int*)  d_in[4];
    const int*   len1 = (const int*)  d_in[5];
    const float* emb1 = (const float*)d_in[6];
    const float* pw1  = (const float*)d_in[7];
    const int*   idx2 = (const int*)  d_in[8];
    const int*   len2 = (const int*)  d_in[9];
    const float* emb2 = (const float*)d_in[10];
    const float* pw2  = (const float*)d_in[11];
    const int*   idx3 = (const int*)  d_in[12];
    const int*   len3 = (const int*)  d_in[13];
    const float* emb3 = (const float*)d_in[14];
    const float* pw3  = (const float*)d_in[15];

    float* out = (float*)d_out;          // out[0] = loss, out+1 = pred
    float* partials = (float*)d_ws;      // NPART floats

    pool4_kernel<<<NB, 256, 0, stream>>>(
        idx0, len0, emb0, pw0,
        idx1, len1, emb1, pw1,
        idx2, len2, emb2, pw2,
        idx3, len3, emb3, pw3,
        out + 1, partials);

    reduce_kernel<<<1, 1024, 0, stream>>>(partials, out);
}

// Round 7
// 42.993 us; speedup vs baseline: 1.3840x; 1.0311x over previous
//
#include <hip/hip_runtime.h>

#define NB 16384       // bags
#define DIM 128
#define PRED_W 512     // 4 * DIM
#define NPART NB       // one partial per block

typedef float f32x4 __attribute__((ext_vector_type(4)));

// R2 gather structure (best measured: 39.2us). Guarded wave-uniform loads --
// clamped/unconditional variants cost +11% (R3/R5) because wasted loads eat
// TA/L1 issue bandwidth. Forced MLP=12 via asm was a null (R5): the gather
// path is device-saturated, not latency-bound per wave.
template<int L>
__device__ __forceinline__ void pool_one(
    const int* __restrict__ idx, const int* __restrict__ len,
    const float* __restrict__ emb, const float* __restrict__ pw,
    int b, int lane, float& ax, float& ay)
{
    const int n = len[b];                       // wave-uniform
    const int* __restrict__ bag = idx + (size_t)b * L;

    int r[L];
    #pragma unroll
    for (int l = 0; l < L; ++l) r[l] = bag[l];

    float2 v[L];
    #pragma unroll
    for (int l = 0; l < L; ++l)
        if (l < n)                              // wave-uniform, no divergence
            v[l] = *reinterpret_cast<const float2*>(
                emb + (size_t)r[l] * DIM + 2 * lane);   // 512B coalesced row

    #pragma unroll
    for (int l = 0; l < L; ++l)
        if (l < n) {
            const float w = pw[l];
            ax = fmaf(w, v[l].x, ax);
            ay = fmaf(w, v[l].y, ay);
        }
}

__global__ __launch_bounds__(256) void pool4_kernel(
    const int* __restrict__ idx0, const int* __restrict__ len0,
    const float* __restrict__ emb0, const float* __restrict__ pw0,
    const int* __restrict__ idx1, const int* __restrict__ len1,
    const float* __restrict__ emb1, const float* __restrict__ pw1,
    const int* __restrict__ idx2, const int* __restrict__ len2,
    const float* __restrict__ emb2, const float* __restrict__ pw2,
    const int* __restrict__ idx3, const int* __restrict__ len3,
    const float* __restrict__ emb3, const float* __restrict__ pw3,
    float* __restrict__ pred,      // d_out + 1 (4-byte aligned only)
    float* __restrict__ partials)  // d_ws, NPART floats
{
    const int b    = blockIdx.x;
    const int wave = threadIdx.x >> 6;   // 0..3 -> feature id
    const int lane = threadIdx.x & 63;

    float ax = 0.f, ay = 0.f;
    switch (wave) {
        case 0:  pool_one<10>(idx0, len0, emb0, pw0, b, lane, ax, ay); break;
        case 1:  pool_one<10>(idx1, len1, emb1, pw1, b, lane, ax, ay); break;
        case 2:  pool_one<12>(idx2, len2, emb2, pw2, b, lane, ax, ay); break;
        default: pool_one<12>(idx3, len3, emb3, pw3, b, lane, ax, ay); break;
    }

    // pred store: non-temporal (write-once; keep it out of L2/L3 so the
    // embedding rows keep the cache capacity). Scalar because pred base is
    // only 4B aligned.
    float* o = pred + (size_t)b * PRED_W + wave * DIM + 2 * lane;
    __builtin_nontemporal_store(ax, o);
    __builtin_nontemporal_store(ay, o + 1);

    // loss partial: wave reduce -> block reduce -> one partial per block
    float s = ax + ay;
    #pragma unroll
    for (int off = 32; off; off >>= 1) s += __shfl_down(s, off, 64);

    __shared__ float ws[4];
    if (lane == 0) ws[wave] = s;
    __syncthreads();
    if (threadIdx.x == 0)
        __builtin_nontemporal_store(ws[0] + ws[1] + ws[2] + ws[3], partials + b);
}

__global__ __launch_bounds__(1024) void reduce_kernel(
    const float* __restrict__ partials, float* __restrict__ loss_out)
{
    // 16384 floats = 4096 float4s, 1024 threads x 4
    float s = 0.f;
    const f32x4* p4 = reinterpret_cast<const f32x4*>(partials);
    #pragma unroll
    for (int i = 0; i < 4; ++i) {
        f32x4 v = __builtin_nontemporal_load(p4 + threadIdx.x + i * 1024);
        s += (v.x + v.y) + (v.z + v.w);
    }

    #pragma unroll
    for (int off = 32; off; off >>= 1) s += __shfl_down(s, off, 64);

    __shared__ float ws[16];
    const int wave = threadIdx.x >> 6, lane = threadIdx.x & 63;
    if (lane == 0) ws[wave] = s;
    __syncthreads();
    if (threadIdx.x == 0) {
        float t = 0.f;
        #pragma unroll
        for (int i = 0; i < 16; ++i) t += ws[i];
        loss_out[0] = t / (float)((size_t)NB * PRED_W);
    }
}

extern "C" void kernel_launch(void* const* d_in, const int* in_sizes, int n_in,
                              void* d_out, int out_size, void* d_ws, size_t ws_size,
                              hipStream_t stream) {
    // setup_inputs() dict order: per feature f: idx{f}, len{f}, emb{f}, pw{f}
    const int*   idx0 = (const int*)  d_in[0];
    const int*   len0 = (const int*)  d_in[1];
    const float* emb0 = (const float*)d_in[2];
    const float* pw0  = (const float*)d_in[3];
    const int*   idx1 = (const int*)  d_in[4];
    const int*   len1 = (const int*)  d_in[5];
    const float* emb1 = (const float*)d_in[6];
    const float* pw1  = (const float*)d_in[7];
    const int*   idx2 = (const int*)  d_in[8];
    const int*   len2 = (const int*)  d_in[9];
    const float* emb2 = (const float*)d_in[10];
    const float* pw2  = (const float*)d_in[11];
    const int*   idx3 = (const int*)  d_in[12];
    const int*   len3 = (const int*)  d_in[13];
    const float* emb3 = (const float*)d_in[14];
    const float* pw3  = (const float*)d_in[15];

    float* out = (float*)d_out;          // out[0] = loss, out+1 = pred
    float* partials = (float*)d_ws;      // NPART floats

    pool4_kernel<<<NB, 256, 0, stream>>>(
        idx0, len0, emb0, pw0,
        idx1, len1, emb1, pw1,
        idx2, len2, emb2, pw2,
        idx3, len3, emb3, pw3,
        out + 1, partials);

    reduce_kernel<<<1, 1024, 0, stream>>>(partials, out);
}

// Round 8
// 42.504 us; speedup vs baseline: 1.3999x; 1.0115x over previous
//
#include <hip/hip_runtime.h>

#define NB 16384       // bags
#define DIM 128
#define PRED_W 512     // 4 * DIM
#define BAGS_PER_BLOCK 4
#define NBLK (NB / BAGS_PER_BLOCK)   // 4096
#define NPART NBLK                   // one partial per block

typedef float f32x4 __attribute__((ext_vector_type(4)));

// R2 gather structure (best measured: 39.2us). Guarded wave-uniform loads --
// clamped/unconditional variants cost +11% (R3/R5: wasted loads eat issue BW).
// Forced MLP=12 via asm was a null (R5): gather path is throughput-bound, not
// per-wave-latency-bound. NT stores regressed (R7): revert to plain stores.
template<int L>
__device__ __forceinline__ void pool_one(
    const int* __restrict__ idx, const int* __restrict__ len,
    const float* __restrict__ emb, const float* __restrict__ pw,
    int b, int lane, float& ax, float& ay)
{
    const int n = len[b];                       // wave-uniform
    const int* __restrict__ bag = idx + (size_t)b * L;

    int r[L];
    #pragma unroll
    for (int l = 0; l < L; ++l) r[l] = bag[l];

    float2 v[L];
    #pragma unroll
    for (int l = 0; l < L; ++l)
        if (l < n)                              // wave-uniform, no divergence
            v[l] = *reinterpret_cast<const float2*>(
                emb + (size_t)r[l] * DIM + 2 * lane);   // 512B coalesced row

    #pragma unroll
    for (int l = 0; l < L; ++l)
        if (l < n) {
            const float w = pw[l];
            ax = fmaf(w, v[l].x, ax);
            ay = fmaf(w, v[l].y, ay);
        }
}

__global__ __launch_bounds__(256) void pool4_kernel(
    const int* __restrict__ idx0, const int* __restrict__ len0,
    const float* __restrict__ emb0, const float* __restrict__ pw0,
    const int* __restrict__ idx1, const int* __restrict__ len1,
    const float* __restrict__ emb1, const float* __restrict__ pw1,
    const int* __restrict__ idx2, const int* __restrict__ len2,
    const float* __restrict__ emb2, const float* __restrict__ pw2,
    const int* __restrict__ idx3, const int* __restrict__ len3,
    const float* __restrict__ emb3, const float* __restrict__ pw3,
    float* __restrict__ pred,      // d_out + 1 (4-byte aligned only)
    float* __restrict__ partials)  // d_ws, NPART floats
{
    const int wave = threadIdx.x >> 6;   // 0..3 -> feature id
    const int lane = threadIdx.x & 63;

    float ssum = 0.f;                    // loss partial across 4 bags

    #pragma unroll
    for (int k = 0; k < BAGS_PER_BLOCK; ++k) {
        const int b = blockIdx.x * BAGS_PER_BLOCK + k;

        float ax = 0.f, ay = 0.f;
        switch (wave) {
            case 0:  pool_one<10>(idx0, len0, emb0, pw0, b, lane, ax, ay); break;
            case 1:  pool_one<10>(idx1, len1, emb1, pw1, b, lane, ax, ay); break;
            case 2:  pool_one<12>(idx2, len2, emb2, pw2, b, lane, ax, ay); break;
            default: pool_one<12>(idx3, len3, emb3, pw3, b, lane, ax, ay); break;
        }

        // pred store: scalar (pred base is only 4B aligned)
        float* o = pred + (size_t)b * PRED_W + wave * DIM + 2 * lane;
        o[0] = ax;
        o[1] = ay;

        ssum += ax + ay;
    }

    // loss partial: wave reduce -> block reduce -> one partial per block
    #pragma unroll
    for (int off = 32; off; off >>= 1) ssum += __shfl_down(ssum, off, 64);

    __shared__ float ws[4];
    if (lane == 0) ws[wave] = ssum;
    __syncthreads();
    if (threadIdx.x == 0) partials[blockIdx.x] = ws[0] + ws[1] + ws[2] + ws[3];
}

__global__ __launch_bounds__(1024) void reduce_kernel(
    const float* __restrict__ partials, float* __restrict__ loss_out)
{
    // 4096 floats = 1024 f32x4, one per thread
    const f32x4 v = reinterpret_cast<const f32x4*>(partials)[threadIdx.x];
    float s = (v.x + v.y) + (v.z + v.w);

    #pragma unroll
    for (int off = 32; off; off >>= 1) s += __shfl_down(s, off, 64);

    __shared__ float ws[16];
    const int wave = threadIdx.x >> 6, lane = threadIdx.x & 63;
    if (lane == 0) ws[wave] = s;
    __syncthreads();
    if (threadIdx.x == 0) {
        float t = 0.f;
        #pragma unroll
        for (int i = 0; i < 16; ++i) t += ws[i];
        loss_out[0] = t / (float)((size_t)NB * PRED_W);
    }
}

extern "C" void kernel_launch(void* const* d_in, const int* in_sizes, int n_in,
                              void* d_out, int out_size, void* d_ws, size_t ws_size,
                              hipStream_t stream) {
    // setup_inputs() dict order: per feature f: idx{f}, len{f}, emb{f}, pw{f}
    const int*   idx0 = (const int*)  d_in[0];
    const int*   len0 = (const int*)  d_in[1];
    const float* emb0 = (const float*)d_in[2];
    const float* pw0  = (const float*)d_in[3];
    const int*   idx1 = (const int*)  d_in[4];
    const int*   len1 = (const int*)  d_in[5];
    const float* emb1 = (const float*)d_in[6];
    const float* pw1  = (const float*)d_in[7];
    const int*   idx2 = (const int*)  d_in[8];
    const int*   len2 = (const int*)  d_in[9];
    const float* emb2 = (const float*)d_in[10];
    const float* pw2  = (const float*)d_in[11];
    const int*   idx3 = (const int*)  d_in[12];
    const int*   len3 = (const int*)  d_in[13];
    const float* emb3 = (const float*)d_in[14];
    const float* pw3  = (const float*)d_in[15];

    float* out = (float*)d_out;          // out[0] = loss, out+1 = pred
    float* partials = (float*)d_ws;      // NPART floats

    pool4_kernel<<<NBLK, 256, 0, stream>>>(
        idx0, len0, emb0, pw0,
        idx1, len1, emb1, pw1,
        idx2, len2, emb2, pw2,
        idx3, len3, emb3, pw3,
        out + 1, partials);

    reduce_kernel<<<1, 1024, 0, stream>>>(partials, out);
}

// Round 9
// 39.020 us; speedup vs baseline: 1.5249x; 1.0893x over previous
//
#include <hip/hip_runtime.h>

#define NB 16384       // bags
#define DIM 128
#define PRED_W 512     // 4 * DIM
#define NPART NB       // one partial per block

typedef float f32x4 __attribute__((ext_vector_type(4)));

// Empirical argmin after 8 rounds of A/B (39.2us bench; ~3.7 TB/s HBM on
// random 512B rows = 59% of streaming ceiling; demand-byte rate ~6.25 TB/s
// = m13 ceiling). Levers probed and rejected:
//   - forced MLP=12 via inline asm (R5): null -> not per-wave-latency-bound
//   - unconditional clamped loads (R3/R5): +11% (wasted TA/L1 issue slots)
//   - 2-rows-per-dwordx4 (R4): +50% (junk odd-element gathers, +9% fetch)
//   - nontemporal stores (R7): +10% (write-through inflation, no L3 gain)
//   - 4 bags/block (R8): +8% (serialized dependency chains)
template<int L>
__device__ __forceinline__ void pool_one(
    const int* __restrict__ idx, const int* __restrict__ len,
    const float* __restrict__ emb, const float* __restrict__ pw,
    int b, int lane, float& ax, float& ay)
{
    const int n = len[b];                       // wave-uniform
    const int* __restrict__ bag = idx + (size_t)b * L;

    int r[L];
    #pragma unroll
    for (int l = 0; l < L; ++l) r[l] = bag[l];

    float2 v[L];
    #pragma unroll
    for (int l = 0; l < L; ++l)
        if (l < n)                              // wave-uniform, no divergence
            v[l] = *reinterpret_cast<const float2*>(
                emb + (size_t)r[l] * DIM + 2 * lane);   // 512B coalesced row

    #pragma unroll
    for (int l = 0; l < L; ++l)
        if (l < n) {
            const float w = pw[l];
            ax = fmaf(w, v[l].x, ax);
            ay = fmaf(w, v[l].y, ay);
        }
}

__global__ __launch_bounds__(256) void pool4_kernel(
    const int* __restrict__ idx0, const int* __restrict__ len0,
    const float* __restrict__ emb0, const float* __restrict__ pw0,
    const int* __restrict__ idx1, const int* __restrict__ len1,
    const float* __restrict__ emb1, const float* __restrict__ pw1,
    const int* __restrict__ idx2, const int* __restrict__ len2,
    const float* __restrict__ emb2, const float* __restrict__ pw2,
    const int* __restrict__ idx3, const int* __restrict__ len3,
    const float* __restrict__ emb3, const float* __restrict__ pw3,
    float* __restrict__ pred,      // d_out + 1 (4-byte aligned only)
    float* __restrict__ partials)  // d_ws, NPART floats
{
    const int b    = blockIdx.x;
    const int wave = threadIdx.x >> 6;   // 0..3 -> feature id
    const int lane = threadIdx.x & 63;

    float ax = 0.f, ay = 0.f;
    switch (wave) {
        case 0:  pool_one<10>(idx0, len0, emb0, pw0, b, lane, ax, ay); break;
        case 1:  pool_one<10>(idx1, len1, emb1, pw1, b, lane, ax, ay); break;
        case 2:  pool_one<12>(idx2, len2, emb2, pw2, b, lane, ax, ay); break;
        default: pool_one<12>(idx3, len3, emb3, pw3, b, lane, ax, ay); break;
    }

    // pred store: scalar (pred base is only 4B aligned)
    float* o = pred + (size_t)b * PRED_W + wave * DIM + 2 * lane;
    o[0] = ax;
    o[1] = ay;

    // loss partial: wave reduce -> block reduce -> one partial per block
    float s = ax + ay;
    #pragma unroll
    for (int off = 32; off; off >>= 1) s += __shfl_down(s, off, 64);

    __shared__ float ws[4];
    if (lane == 0) ws[wave] = s;
    __syncthreads();
    if (threadIdx.x == 0) partials[b] = ws[0] + ws[1] + ws[2] + ws[3];
}

__global__ __launch_bounds__(1024) void reduce_kernel(
    const float* __restrict__ partials, float* __restrict__ loss_out)
{
    // 16384 floats = 4096 f32x4, 1024 threads x 4
    float s = 0.f;
    const f32x4* p4 = reinterpret_cast<const f32x4*>(partials);
    #pragma unroll
    for (int i = 0; i < 4; ++i) {
        f32x4 v = p4[threadIdx.x + i * 1024];
        s += (v.x + v.y) + (v.z + v.w);
    }

    #pragma unroll
    for (int off = 32; off; off >>= 1) s += __shfl_down(s, off, 64);

    __shared__ float ws[16];
    const int wave = threadIdx.x >> 6, lane = threadIdx.x & 63;
    if (lane == 0) ws[wave] = s;
    __syncthreads();
    if (threadIdx.x == 0) {
        float t = 0.f;
        #pragma unroll
        for (int i = 0; i < 16; ++i) t += ws[i];
        loss_out[0] = t / (float)((size_t)NB * PRED_W);
    }
}

extern "C" void kernel_launch(void* const* d_in, const int* in_sizes, int n_in,
                              void* d_out, int out_size, void* d_ws, size_t ws_size,
                              hipStream_t stream) {
    // setup_inputs() dict order: per feature f: idx{f}, len{f}, emb{f}, pw{f}
    const int*   idx0 = (const int*)  d_in[0];
    const int*   len0 = (const int*)  d_in[1];
    const float* emb0 = (const float*)d_in[2];
    const float* pw0  = (const float*)d_in[3];
    const int*   idx1 = (const int*)  d_in[4];
    const int*   len1 = (const int*)  d_in[5];
    const float* emb1 = (const float*)d_in[6];
    const float* pw1  = (const float*)d_in[7];
    const int*   idx2 = (const int*)  d_in[8];
    const int*   len2 = (const int*)  d_in[9];
    const float* emb2 = (const float*)d_in[10];
    const float* pw2  = (const float*)d_in[11];
    const int*   idx3 = (const int*)  d_in[12];
    const int*   len3 = (const int*)  d_in[13];
    const float* emb3 = (const float*)d_in[14];
    const float* pw3  = (const float*)d_in[15];

    float* out = (float*)d_out;          // out[0] = loss, out+1 = pred
    float* partials = (float*)d_ws;      // NPART floats

    pool4_kernel<<<NB, 256, 0, stream>>>(
        idx0, len0, emb0, pw0,
        idx1, len1, emb1, pw1,
        idx2, len2, emb2, pw2,
        idx3, len3, emb3, pw3,
        out + 1, partials);

    reduce_kernel<<<1, 1024, 0, stream>>>(partials, out);
}